// Round 1
// baseline (557.616 us; speedup 1.0000x reference)
//
#include <hip/hip_runtime.h>

#define B_ 128
#define T_ 256
#define H_ 768
#define K_ 64
#define BT_ (B_ * T_)

// ---------------------------------------------------------------------------
// DPP helpers: wave-wide max in ~6 VALU ops (row_shr/bcast ladder).
// ---------------------------------------------------------------------------
template <int CTRL>
__device__ __forceinline__ float dpp_mov_f(float x) {
    return __int_as_float(__builtin_amdgcn_update_dpp(
        __float_as_int(x), __float_as_int(x), CTRL, 0xF, 0xF, false));
}
__device__ __forceinline__ float wave_max64(float x) {
    x = fmaxf(x, dpp_mov_f<0x111>(x));  // row_shr:1
    x = fmaxf(x, dpp_mov_f<0x112>(x));  // row_shr:2
    x = fmaxf(x, dpp_mov_f<0x114>(x));  // row_shr:4
    x = fmaxf(x, dpp_mov_f<0x118>(x));  // row_shr:8
    x = fmaxf(x, dpp_mov_f<0x142>(x));  // row_bcast:15
    x = fmaxf(x, dpp_mov_f<0x143>(x));  // row_bcast:31
    return __int_as_float(__builtin_amdgcn_readlane(__float_as_int(x), 63));
}
__device__ __forceinline__ float readlane0_f(float x) {
    return __int_as_float(__builtin_amdgcn_readfirstlane(__float_as_int(x)));
}
template <int I>
__device__ __forceinline__ float readlane_f(float x) {
    return __int_as_float(__builtin_amdgcn_readlane(__float_as_int(x), I));
}

// ---------------------------------------------------------------------------
// Kernel A: emissions = hidden @ W + b.
// Round 6: 512 threads (8 waves, 8 cols/wave) on the same 128x64 tile.
// Grid is 256 blocks = 1 block/CU; 256-thread blocks gave only 1 wave/SIMD so
// every s_waitcnt on the uniform W loads was exposed. 8 waves -> 2 waves/SIMD.
// Per-output accumulation order (ascending h, single accumulator) unchanged
// -> emissions bit-identical to the passing round-5 kernel.
// ---------------------------------------------------------------------------
#define BK_ 32
#define P_ 130
__global__ __launch_bounds__(512) void gemm_emis(const float* __restrict__ hidden,
                                                 const float* __restrict__ W,
                                                 const float* __restrict__ bias,
                                                 float* __restrict__ emis) {
    __shared__ float At[BK_ * P_];

    const int tid = threadIdx.x;
    const int lane = tid & 63;
    const int wc = __builtin_amdgcn_readfirstlane((tid >> 6) * 8);  // 8 cols/wave
    const int rowbase = blockIdx.x * 128;
    const int srow = tid >> 2;         // 0..127: one LDS-stage row per thread
    const int scol = (tid & 3) * 8;    // 8 consecutive h per thread

    float acc0[8], acc1[8];
#pragma unroll
    for (int c = 0; c < 8; ++c) { acc0[c] = bias[wc + c]; acc1[c] = acc0[c]; }

    float4 pf0 = *(const float4*)&hidden[(size_t)(rowbase + srow) * H_ + scol];
    float4 pf1 = *(const float4*)&hidden[(size_t)(rowbase + srow) * H_ + scol + 4];

    for (int kb = 0; kb < H_ / BK_; ++kb) {
        __syncthreads();
        At[(scol + 0) * P_ + srow] = pf0.x;
        At[(scol + 1) * P_ + srow] = pf0.y;
        At[(scol + 2) * P_ + srow] = pf0.z;
        At[(scol + 3) * P_ + srow] = pf0.w;
        At[(scol + 4) * P_ + srow] = pf1.x;
        At[(scol + 5) * P_ + srow] = pf1.y;
        At[(scol + 6) * P_ + srow] = pf1.z;
        At[(scol + 7) * P_ + srow] = pf1.w;
        __syncthreads();
        if (kb + 1 < H_ / BK_) {
            pf0 = *(const float4*)&hidden[(size_t)(rowbase + srow) * H_ +
                                          (kb + 1) * BK_ + scol];
            pf1 = *(const float4*)&hidden[(size_t)(rowbase + srow) * H_ +
                                          (kb + 1) * BK_ + scol + 4];
        }
        const float* Wk = &W[(kb * BK_) * K_ + wc];
#pragma unroll 8
        for (int h = 0; h < BK_; ++h) {
            float2 a = *(const float2*)&At[h * P_ + 2 * lane];
            float4 w0 = *(const float4*)&Wk[h * K_ + 0];
            float4 w1 = *(const float4*)&Wk[h * K_ + 4];
            acc0[0] += a.x * w0.x; acc1[0] += a.y * w0.x;
            acc0[1] += a.x * w0.y; acc1[1] += a.y * w0.y;
            acc0[2] += a.x * w0.z; acc1[2] += a.y * w0.z;
            acc0[3] += a.x * w0.w; acc1[3] += a.y * w0.w;
            acc0[4] += a.x * w1.x; acc1[4] += a.y * w1.x;
            acc0[5] += a.x * w1.y; acc1[5] += a.y * w1.y;
            acc0[6] += a.x * w1.z; acc1[6] += a.y * w1.z;
            acc0[7] += a.x * w1.w; acc1[7] += a.y * w1.w;
        }
    }

    float* e0 = &emis[(size_t)(rowbase + 2 * lane) * K_ + wc];
    float* e1 = &emis[(size_t)(rowbase + 2 * lane + 1) * K_ + wc];
    *(float4*)&e0[0] = make_float4(acc0[0], acc0[1], acc0[2], acc0[3]);
    *(float4*)&e0[4] = make_float4(acc0[4], acc0[5], acc0[6], acc0[7]);
    *(float4*)&e1[0] = make_float4(acc1[0], acc1[1], acc1[2], acc1[3]);
    *(float4*)&e1[4] = make_float4(acc1[4], acc1[5], acc1[6], acc1[7]);
}

// ---------------------------------------------------------------------------
// Kernel B: fused CRF. Round 6: TWO batches per block (grid 64 x 128 thr).
// The serial scans are latency-bound (VALUBusy 12%, ~670 cy/step vs ~420 cy
// issue minimum); interleaving two independent batch chains per wave fills the
// stalls. Emissions are read straight from global (L2-resident, prefetched one
// step ahead) which frees LDS for the second batch's v-history.
// Viterbi inner uses max3 pairing (exact) to cut 64 v_max to 32.
// ---------------------------------------------------------------------------
__global__ __launch_bounds__(128, 1) void crf_kernel(const float* __restrict__ emis,
                                                     const int* __restrict__ masks,
                                                     const int* __restrict__ target,
                                                     const float* __restrict__ trans,
                                                     float* __restrict__ out) {
    __shared__ __align__(16) float vbufA[T_ * K_];  // 64 KB viterbi history, batch A
    __shared__ __align__(16) float vbufB[T_ * K_];  // 64 KB viterbi history, batch B
    __shared__ float tbuf[K_ * 65];                 // padded trans rows (backtrack)
    __shared__ int tagsA[T_];                       // decoded tags (avoids scratch)
    __shared__ int tagsB[T_];

    const int tid = threadIdx.x;
    const int lane = tid & 63;
    const int bA = blockIdx.x * 2;
    const int bB = bA + 1;
    const float* eA = emis + (size_t)bA * (T_ * K_);
    const float* eB = emis + (size_t)bB * (T_ * K_);

    int sa = 0, sb = 0;
#pragma unroll
    for (int k = 0; k < 4; ++k) {
        sa += masks[bA * T_ + lane + k * 64];
        sb += masks[bB * T_ + lane + k * 64];
    }
#pragma unroll
    for (int m = 32; m; m >>= 1) {
        sa += __shfl_xor(sa, m, 64);
        sb += __shfl_xor(sb, m, 64);
    }
    const int slA = sa, slB = sb;

    if (tid < 64) {
        // ============ forward (wave 0), delayed normalization, 2 batches =====
        float Ecol[64];
#pragma unroll
        for (int i = 0; i < 64; ++i) Ecol[i] = __expf(trans[i * K_ + lane]);

        float ecA = eA[lane], ecB = eB[lane];
        float CA = readlane0_f(ecA), CB = readlane0_f(ecB);
        float pA = __expf(ecA - CA), pB = __expf(ecB - CB);
        float lDA = 0.f, lDB = 0.f;
        float enA = eA[K_ + lane], enB = eB[K_ + lane];
        float e0A = readlane0_f(enA), e0B = readlane0_f(enB);
        float xgA = __expf(enA - e0A), xgB = __expf(enB - e0B);

        for (int t = 1; t < T_; ++t) {
            float efA = (t < T_ - 1) ? eA[(t + 1) * K_ + lane] : 0.f;
            float efB = (t < T_ - 1) ? eB[(t + 1) * K_ + lane] : 0.f;
            float a0 = 0.f, a1 = 0.f, a2 = 0.f, a3 = 0.f;
            float a4 = 0.f, a5 = 0.f, a6 = 0.f, a7 = 0.f;
            float c0 = 0.f, c1 = 0.f, c2 = 0.f, c3 = 0.f;
            float c4 = 0.f, c5 = 0.f, c6 = 0.f, c7 = 0.f;
            // two independent all-to-alls, interleaved: pure VALU on the chain
#define FWD8(base)                                                        \
            a0 = fmaf(readlane_f<(base) + 0>(pA), Ecol[(base) + 0], a0);  \
            c0 = fmaf(readlane_f<(base) + 0>(pB), Ecol[(base) + 0], c0);  \
            a1 = fmaf(readlane_f<(base) + 1>(pA), Ecol[(base) + 1], a1);  \
            c1 = fmaf(readlane_f<(base) + 1>(pB), Ecol[(base) + 1], c1);  \
            a2 = fmaf(readlane_f<(base) + 2>(pA), Ecol[(base) + 2], a2);  \
            c2 = fmaf(readlane_f<(base) + 2>(pB), Ecol[(base) + 2], c2);  \
            a3 = fmaf(readlane_f<(base) + 3>(pA), Ecol[(base) + 3], a3);  \
            c3 = fmaf(readlane_f<(base) + 3>(pB), Ecol[(base) + 3], c3);  \
            a4 = fmaf(readlane_f<(base) + 4>(pA), Ecol[(base) + 4], a4);  \
            c4 = fmaf(readlane_f<(base) + 4>(pB), Ecol[(base) + 4], c4);  \
            a5 = fmaf(readlane_f<(base) + 5>(pA), Ecol[(base) + 5], a5);  \
            c5 = fmaf(readlane_f<(base) + 5>(pB), Ecol[(base) + 5], c5);  \
            a6 = fmaf(readlane_f<(base) + 6>(pA), Ecol[(base) + 6], a6);  \
            c6 = fmaf(readlane_f<(base) + 6>(pB), Ecol[(base) + 6], c6);  \
            a7 = fmaf(readlane_f<(base) + 7>(pA), Ecol[(base) + 7], a7);  \
            c7 = fmaf(readlane_f<(base) + 7>(pB), Ecol[(base) + 7], c7);
            FWD8(0) FWD8(8) FWD8(16) FWD8(24) FWD8(32) FWD8(40) FWD8(48) FWD8(56)
#undef FWD8
            float DA = ((a0 + a1) + (a2 + a3)) + ((a4 + a5) + (a6 + a7));
            float DB = ((c0 + c1) + (c2 + c3)) + ((c4 + c5) + (c6 + c7));
            float pnA = DA * xgA;
            float pnB = DB * xgB;
            if (t < slA) { pA = pnA; CA += e0A + lDA; }
            if (t < slB) { pB = pnB; CB += e0B + lDB; }
            // off-chain prep for next step
            float dA = readlane0_f(DA), dB = readlane0_f(DB);
            lDA = __logf(dA); lDB = __logf(dB);
            float gA = __fdividef(1.f, dA), gB = __fdividef(1.f, dB);
            e0A = readlane0_f(efA); e0B = readlane0_f(efB);
            xgA = __expf(efA - e0A) * gA;
            xgB = __expf(efB - e0B) * gB;
        }
        float rsA = pA, rsB = pB;
#pragma unroll
        for (int m = 32; m; m >>= 1) {
            rsA += __shfl_xor(rsA, m, 64);
            rsB += __shfl_xor(rsB, m, 64);
        }
        float lnA = CA + __logf(rsA);
        float lnB = CB + __logf(rsB);

        // ---------------- sequence scores ----------------
        float scA = 0.f, scB = 0.f;
#pragma unroll
        for (int k = 0; k < 4; ++k) {
            int t = lane + k * 64;
            if (t < slA) {
                int tg = target[bA * T_ + t];
                scA += eA[t * K_ + tg];
                if (t >= 1) scA += trans[target[bA * T_ + t - 1] * K_ + tg];
            }
            if (t < slB) {
                int tg = target[bB * T_ + t];
                scB += eB[t * K_ + tg];
                if (t >= 1) scB += trans[target[bB * T_ + t - 1] * K_ + tg];
            }
        }
#pragma unroll
        for (int m = 32; m; m >>= 1) {
            scA += __shfl_xor(scA, m, 64);
            scB += __shfl_xor(scB, m, 64);
        }
        if (lane == 0) {
            out[BT_ + bA] = scA - lnA;
            out[BT_ + bB] = scB - lnB;
        }
    } else {
        // ============ Viterbi (wave 1): readlane max-plus, 2 batches =========
        float Tcol[64];
#pragma unroll
        for (int i = 0; i < 64; ++i) Tcol[i] = trans[i * K_ + lane];
        for (int idx = lane; idx < K_ * K_; idx += 64)
            tbuf[(idx >> 6) * 65 + (idx & 63)] = trans[idx];

        float vA = eA[lane], vB = eB[lane];
        vbufA[lane] = vA;
        vbufB[lane] = vB;
        float enA = eA[K_ + lane], enB = eB[K_ + lane];

        for (int t = 1; t < T_; ++t) {
            float efA = (t < T_ - 1) ? eA[(t + 1) * K_ + lane] : 0.f;
            float efB = (t < T_ - 1) ? eB[(t + 1) * K_ + lane] : 0.f;
            float mA0 = -3.4e38f, mA1 = -3.4e38f, mA2 = -3.4e38f, mA3 = -3.4e38f;
            float mB0 = -3.4e38f, mB1 = -3.4e38f, mB2 = -3.4e38f, mB3 = -3.4e38f;
            // pair states into max3 (exact regroup); interleave the two chains
#define VITP(macc, vv, i0, i1)                                            \
            {                                                             \
                float x_ = readlane_f<(i0)>(vv) + Tcol[(i0)];             \
                float y_ = readlane_f<(i1)>(vv) + Tcol[(i1)];             \
                macc = fmaxf(fmaxf(macc, x_), y_);                        \
            }
#define VIT8(base)                                                        \
            VITP(mA0, vA, (base) + 0, (base) + 1)                         \
            VITP(mB0, vB, (base) + 0, (base) + 1)                         \
            VITP(mA1, vA, (base) + 2, (base) + 3)                         \
            VITP(mB1, vB, (base) + 2, (base) + 3)                         \
            VITP(mA2, vA, (base) + 4, (base) + 5)                         \
            VITP(mB2, vB, (base) + 4, (base) + 5)                         \
            VITP(mA3, vA, (base) + 6, (base) + 7)                         \
            VITP(mB3, vB, (base) + 6, (base) + 7)
            VIT8(0) VIT8(8) VIT8(16) VIT8(24) VIT8(32) VIT8(40) VIT8(48) VIT8(56)
#undef VIT8
#undef VITP
            float MA = fmaxf(fmaxf(mA0, mA1), fmaxf(mA2, mA3));
            float MB = fmaxf(fmaxf(mB0, mB1), fmaxf(mB2, mB3));
            float vnA = MA + enA;
            float vnB = MB + enB;
            if (t < slA) vA = vnA;
            if (t < slB) vB = vnB;
            vbufA[t * K_ + lane] = vA;   // off-chain ds_write (history)
            vbufB[t * K_ + lane] = vB;
            enA = efA; enB = efB;
        }

        // last tags: first index of max over lanes (np.argmax tie rule)
        {
            float MA = wave_max64(vA);
            unsigned long long blA = __ballot(vA >= MA);
            int tgA = (int)__builtin_ctzll(blA);
            float MB = wave_max64(vB);
            unsigned long long blB = __ballot(vB >= MB);
            int tgB = (int)__builtin_ctzll(blB);
            if (lane == 0) { tagsA[T_ - 1] = tgA; tagsB[T_ - 1] = tgB; }

            int tagA = tgA, tagB = tgB;
            float vpA = vbufA[(T_ - 2) * K_ + lane];
            float vpB = vbufB[(T_ - 2) * K_ + lane];
            for (int t = T_ - 1; t >= 1; --t) {
                float vxA = (t >= 2) ? vbufA[(t - 2) * K_ + lane] : 0.f;
                float vxB = (t >= 2) ? vbufB[(t - 2) * K_ + lane] : 0.f;
                if (t < slA) {
                    float s = vpA + tbuf[lane * 65 + tagA];
                    float Ms = wave_max64(s);
                    unsigned long long bl = __ballot(s >= Ms);
                    tagA = (int)__builtin_ctzll(bl);
                }
                if (t < slB) {
                    float s = vpB + tbuf[lane * 65 + tagB];
                    float Ms = wave_max64(s);
                    unsigned long long bl = __ballot(s >= Ms);
                    tagB = (int)__builtin_ctzll(bl);
                }
                if (lane == 0) { tagsA[t - 1] = tagA; tagsB[t - 1] = tagB; }
                vpA = vxA; vpB = vxB;
            }
        }
#pragma unroll
        for (int k = 0; k < 4; ++k) {
            int t = lane + k * 64;
            out[bA * T_ + t] = (t < slA) ? (float)tagsA[t] : 0.f;
            out[bB * T_ + t] = (t < slB) ? (float)tagsB[t] : 0.f;
        }
    }
}

// ---------------------------------------------------------------------------
extern "C" void kernel_launch(void* const* d_in, const int* in_sizes, int n_in,
                              void* d_out, int out_size, void* d_ws, size_t ws_size,
                              hipStream_t stream) {
    const float* hidden = (const float*)d_in[0];
    const int* masks    = (const int*)d_in[1];
    const int* target   = (const int*)d_in[2];
    const float* W      = (const float*)d_in[3];
    const float* bias   = (const float*)d_in[4];
    const float* trans  = (const float*)d_in[5];
    float* out = (float*)d_out;
    float* emis = (float*)d_ws;

    gemm_emis<<<dim3(BT_ / 128), dim3(512), 0, stream>>>(hidden, W, bias, emis);
    crf_kernel<<<dim3(B_ / 2), dim3(128), 0, stream>>>(emis, masks, target, trans, out);
}

// Round 2
// 372.761 us; speedup vs baseline: 1.4959x; 1.4959x over previous
//
#include <hip/hip_runtime.h>

#define B_ 128
#define T_ 256
#define H_ 768
#define K_ 64
#define BT_ (B_ * T_)

// ---------------------------------------------------------------------------
// DPP helpers: wave-wide max in ~6 VALU ops (row_shr/bcast ladder).
// ---------------------------------------------------------------------------
template <int CTRL>
__device__ __forceinline__ float dpp_mov_f(float x) {
    return __int_as_float(__builtin_amdgcn_update_dpp(
        __float_as_int(x), __float_as_int(x), CTRL, 0xF, 0xF, false));
}
__device__ __forceinline__ float wave_max64(float x) {
    x = fmaxf(x, dpp_mov_f<0x111>(x));  // row_shr:1
    x = fmaxf(x, dpp_mov_f<0x112>(x));  // row_shr:2
    x = fmaxf(x, dpp_mov_f<0x114>(x));  // row_shr:4
    x = fmaxf(x, dpp_mov_f<0x118>(x));  // row_shr:8
    x = fmaxf(x, dpp_mov_f<0x142>(x));  // row_bcast:15
    x = fmaxf(x, dpp_mov_f<0x143>(x));  // row_bcast:31
    return __int_as_float(__builtin_amdgcn_readlane(__float_as_int(x), 63));
}
__device__ __forceinline__ float readlane0_f(float x) {
    return __int_as_float(__builtin_amdgcn_readfirstlane(__float_as_int(x)));
}
template <int I>
__device__ __forceinline__ float readlane_f(float x) {
    return __int_as_float(__builtin_amdgcn_readlane(__float_as_int(x), I));
}

// ---------------------------------------------------------------------------
// Kernel A: emissions = hidden @ W + b.
// Round 2: BM=64 tiles, 512 blocks x 256 thr -> exactly 2 blocks/CU, i.e.
// 2 waves/SIMD. Rounds 0/1 ran 256 blocks (1 block/CU = 1 wave/SIMD) and sat
// ~4x above the ~30us roofline on exposed latency; block-level co-residency
// is the only way to stack waves per SIMD when grid <= CU count.
// Accumulation order per output (bias + ascending h) unchanged -> emissions
// bit-identical to rounds 0/1.
// ---------------------------------------------------------------------------
#define BK_ 32
#define BM_ 64
#define P_ 66
__global__ __launch_bounds__(256) void gemm_emis(const float* __restrict__ hidden,
                                                 const float* __restrict__ W,
                                                 const float* __restrict__ bias,
                                                 float* __restrict__ emis) {
    __shared__ float At[BK_ * P_];   // 8.4 KB -> LDS never limits occupancy

    const int tid = threadIdx.x;
    const int lane = tid & 63;
    const int wc = __builtin_amdgcn_readfirstlane((tid >> 6) * 16);  // 16 cols/wave
    const int rowbase = blockIdx.x * BM_;
    const int srow = tid >> 2;         // 0..63: stage row
    const int scol = (tid & 3) * 8;    // 8 consecutive h per thread

    float acc[16];
#pragma unroll
    for (int c = 0; c < 16; ++c) acc[c] = bias[wc + c];

    float4 pf0 = *(const float4*)&hidden[(size_t)(rowbase + srow) * H_ + scol];
    float4 pf1 = *(const float4*)&hidden[(size_t)(rowbase + srow) * H_ + scol + 4];

    for (int kb = 0; kb < H_ / BK_; ++kb) {
        __syncthreads();
        At[(scol + 0) * P_ + srow] = pf0.x;
        At[(scol + 1) * P_ + srow] = pf0.y;
        At[(scol + 2) * P_ + srow] = pf0.z;
        At[(scol + 3) * P_ + srow] = pf0.w;
        At[(scol + 4) * P_ + srow] = pf1.x;
        At[(scol + 5) * P_ + srow] = pf1.y;
        At[(scol + 6) * P_ + srow] = pf1.z;
        At[(scol + 7) * P_ + srow] = pf1.w;
        __syncthreads();
        if (kb + 1 < H_ / BK_) {
            pf0 = *(const float4*)&hidden[(size_t)(rowbase + srow) * H_ +
                                          (kb + 1) * BK_ + scol];
            pf1 = *(const float4*)&hidden[(size_t)(rowbase + srow) * H_ +
                                          (kb + 1) * BK_ + scol + 4];
        }
        const float* Wk = &W[(kb * BK_) * K_ + wc];
#pragma unroll 8
        for (int h = 0; h < BK_; ++h) {
            float a = At[h * P_ + lane];
            float4 w0 = *(const float4*)&Wk[h * K_ + 0];
            float4 w1 = *(const float4*)&Wk[h * K_ + 4];
            float4 w2 = *(const float4*)&Wk[h * K_ + 8];
            float4 w3 = *(const float4*)&Wk[h * K_ + 12];
            acc[0]  += a * w0.x;  acc[1]  += a * w0.y;
            acc[2]  += a * w0.z;  acc[3]  += a * w0.w;
            acc[4]  += a * w1.x;  acc[5]  += a * w1.y;
            acc[6]  += a * w1.z;  acc[7]  += a * w1.w;
            acc[8]  += a * w2.x;  acc[9]  += a * w2.y;
            acc[10] += a * w2.z;  acc[11] += a * w2.w;
            acc[12] += a * w3.x;  acc[13] += a * w3.y;
            acc[14] += a * w3.z;  acc[15] += a * w3.w;
        }
    }

    float* e = &emis[(size_t)(rowbase + lane) * K_ + wc];
#pragma unroll
    for (int q = 0; q < 4; ++q)
        *(float4*)&e[q * 4] = make_float4(acc[q * 4], acc[q * 4 + 1],
                                          acc[q * 4 + 2], acc[q * 4 + 3]);
}

// ---------------------------------------------------------------------------
// Kernel B: fused CRF — reverted to the round-0 structure (142 us, passed):
// 1 batch/block, 128 blocks x 128 thr, emissions staged in LDS (bulk float4,
// latency amortized), vbuf history in LDS. Round 1 proved the chains are
// per-instruction-bound (2 chains/wave -> 2.0x time) and that per-step global
// emission reads add vmcnt stalls -> both reverted. Only surviving round-1
// change: Viterbi inner uses max3 pairing (exact regroup, validated) to cut
// 64 v_max to 32 on the critical wave.
// ---------------------------------------------------------------------------
__global__ __launch_bounds__(128, 1) void crf_kernel(const float* __restrict__ emis,
                                                     const int* __restrict__ masks,
                                                     const int* __restrict__ target,
                                                     const float* __restrict__ trans,
                                                     float* __restrict__ out) {
    __shared__ __align__(16) float ebuf[T_ * K_];   // 64 KB emissions for batch b
    __shared__ __align__(16) float vbuf[T_ * K_];   // 64 KB viterbi v-history
    __shared__ float tbuf[K_ * 65];                 // padded trans rows (backtrack)

    const int tid = threadIdx.x;
    const int lane = tid & 63;
    const int b = blockIdx.x;
    const float* eb = emis + (size_t)b * (T_ * K_);

    // stage emissions: 4096 float4s over 128 threads
    {
        const float4* src = (const float4*)eb;
        float4* dst = (float4*)ebuf;
#pragma unroll
        for (int k = 0; k < 32; ++k) dst[tid + k * 128] = src[tid + k * 128];
    }
    int sl = 0;
#pragma unroll
    for (int k = 0; k < 4; ++k) sl += masks[b * T_ + lane + k * 64];
#pragma unroll
    for (int m = 32; m; m >>= 1) sl += __shfl_xor(sl, m, 64);
    const int seq_len = sl;
    __syncthreads();

    if (tid < 64) {
        // ================= forward (wave 0), delayed normalization ==========
        float Ecol[64];
#pragma unroll
        for (int i = 0; i < 64; ++i) Ecol[i] = __expf(trans[i * K_ + lane]);

        float e_c = ebuf[lane];
        float e00 = readlane0_f(e_c);
        float p = __expf(e_c - e00);     // e^{alpha_0} = p * e^C
        float C = e00;
        float logD0prev = 0.f;
        float e_n = ebuf[K_ + lane];
        float en0 = readlane0_f(e_n);
        float xg = __expf(e_n - en0);    // x * g

        for (int t = 1; t < T_; ++t) {
            float e_f = (t < T_ - 1) ? ebuf[(t + 1) * K_ + lane] : 0.f;
            float a0 = 0.f, a1 = 0.f, a2 = 0.f, a3 = 0.f;
            float a4 = 0.f, a5 = 0.f, a6 = 0.f, a7 = 0.f;
            // all-to-all via readlane: pure VALU, no DS on the chain
#define FWD8(base)                                                     \
            a0 = fmaf(readlane_f<base + 0>(p), Ecol[base + 0], a0);    \
            a1 = fmaf(readlane_f<base + 1>(p), Ecol[base + 1], a1);    \
            a2 = fmaf(readlane_f<base + 2>(p), Ecol[base + 2], a2);    \
            a3 = fmaf(readlane_f<base + 3>(p), Ecol[base + 3], a3);    \
            a4 = fmaf(readlane_f<base + 4>(p), Ecol[base + 4], a4);    \
            a5 = fmaf(readlane_f<base + 5>(p), Ecol[base + 5], a5);    \
            a6 = fmaf(readlane_f<base + 6>(p), Ecol[base + 6], a6);    \
            a7 = fmaf(readlane_f<base + 7>(p), Ecol[base + 7], a7);
            FWD8(0) FWD8(8) FWD8(16) FWD8(24) FWD8(32) FWD8(40) FWD8(48) FWD8(56)
#undef FWD8
            float D = ((a0 + a1) + (a2 + a3)) + ((a4 + a5) + (a6 + a7));
            float pnew = D * xg;         // only on-chain op after the dot
            if (t < seq_len) { p = pnew; C += en0 + logD0prev; }
            // off-chain prep for next step
            float D0 = readlane0_f(D);
            logD0prev = __logf(D0);
            float gn = __fdividef(1.f, D0);
            en0 = readlane0_f(e_f);
            xg = __expf(e_f - en0) * gn;
            e_n = e_f;
        }
        float rs = p;
#pragma unroll
        for (int m = 32; m; m >>= 1) rs += __shfl_xor(rs, m, 64);
        float log_norm = C + __logf(rs);

        // ---------------- sequence score ----------------
        float sc = 0.f;
#pragma unroll
        for (int k = 0; k < 4; ++k) {
            int t = lane + k * 64;
            if (t < seq_len) {
                int tg = target[b * T_ + t];
                sc += ebuf[t * K_ + tg];
                if (t >= 1) sc += trans[target[b * T_ + t - 1] * K_ + tg];
            }
        }
#pragma unroll
        for (int m = 32; m; m >>= 1) sc += __shfl_xor(sc, m, 64);
        if (lane == 0) out[BT_ + b] = sc - log_norm;
    } else {
        // ================= Viterbi (wave 1): readlane max-plus ==============
        float Tcol[64];
#pragma unroll
        for (int i = 0; i < 64; ++i) Tcol[i] = trans[i * K_ + lane];
        for (int idx = lane; idx < K_ * K_; idx += 64)
            tbuf[(idx >> 6) * 65 + (idx & 63)] = trans[idx];

        float v = ebuf[lane];
        vbuf[lane] = v;
        float e_n = ebuf[K_ + lane];
        for (int t = 1; t < T_; ++t) {
            float e_f = (t < T_ - 1) ? ebuf[(t + 1) * K_ + lane] : 0.f;
            float m0 = -3.4e38f, m1 = -3.4e38f, m2 = -3.4e38f, m3 = -3.4e38f;
            // pair states into max3 (exact regroup; validated in round 1)
#define VITP(macc, i0, i1)                                                \
            {                                                             \
                float x_ = readlane_f<(i0)>(v) + Tcol[(i0)];              \
                float y_ = readlane_f<(i1)>(v) + Tcol[(i1)];              \
                macc = fmaxf(fmaxf(macc, x_), y_);                        \
            }
#define VIT8(base)                                                        \
            VITP(m0, (base) + 0, (base) + 1)                              \
            VITP(m1, (base) + 2, (base) + 3)                              \
            VITP(m2, (base) + 4, (base) + 5)                              \
            VITP(m3, (base) + 6, (base) + 7)
            VIT8(0) VIT8(8) VIT8(16) VIT8(24) VIT8(32) VIT8(40) VIT8(48) VIT8(56)
#undef VIT8
#undef VITP
            float M = fmaxf(fmaxf(m0, m1), fmaxf(m2, m3));
            float vn = M + e_n;
            if (t < seq_len) v = vn;
            vbuf[t * K_ + lane] = v;   // off-chain ds_write (history)
            e_n = e_f;
        }

        // last tag: first index of max over lanes (np.argmax tie rule)
        float M = wave_max64(v);
        unsigned long long ball = __ballot(v >= M);
        int tag = (int)__builtin_ctzll(ball);

        int path[4];
#pragma unroll
        for (int k = 0; k < 4; ++k) path[k] = 0;
        if (lane == ((T_ - 1) & 63)) path[(T_ - 1) >> 6] = tag;

        float vpre = vbuf[(T_ - 2) * K_ + lane];
        for (int t = T_ - 1; t >= 1; --t) {
            float vnext = (t >= 2) ? vbuf[(t - 2) * K_ + lane] : 0.f;
            if (t < seq_len) {
                float s = vpre + tbuf[lane * 65 + tag];
                float Ms = wave_max64(s);
                unsigned long long bl = __ballot(s >= Ms);
                tag = (int)__builtin_ctzll(bl);
            }
            int pidx = t - 1;
            if (lane == (pidx & 63)) path[pidx >> 6] = tag;
            vpre = vnext;
        }
#pragma unroll
        for (int k = 0; k < 4; ++k) {
            int t = lane + k * 64;
            out[b * T_ + t] = (t < seq_len) ? (float)path[k] : 0.f;
        }
    }
}

// ---------------------------------------------------------------------------
extern "C" void kernel_launch(void* const* d_in, const int* in_sizes, int n_in,
                              void* d_out, int out_size, void* d_ws, size_t ws_size,
                              hipStream_t stream) {
    const float* hidden = (const float*)d_in[0];
    const int* masks    = (const int*)d_in[1];
    const int* target   = (const int*)d_in[2];
    const float* W      = (const float*)d_in[3];
    const float* bias   = (const float*)d_in[4];
    const float* trans  = (const float*)d_in[5];
    float* out = (float*)d_out;
    float* emis = (float*)d_ws;

    gemm_emis<<<dim3(BT_ / BM_), dim3(256), 0, stream>>>(hidden, W, bias, emis);
    crf_kernel<<<dim3(B_), dim3(128), 0, stream>>>(emis, masks, target, trans, out);
}